// Round 5
// baseline (846.846 us; speedup 1.0000x reference)
//
#include <hip/hip_runtime.h>
#include <stddef.h>
#include <stdint.h>

// Problem constants (AnatomicalTextEnhancer): B=16, R=29, D=512, N=20000, k=5
#define B_ 16
#define R_ 29
#define D_ 512
#define DF4 128                            // float4 per row
#define N_ 20000
#define K_ 5
#define TROWS 192                          // rows per tile
#define NTIX ((N_ + TROWS - 1) / TROWS)    // 105 tiles per r
#define NTILES (R_ * NTIX)                 // 3045
#define NPASS 8                            // d passes, 256B/row/pass
#define PCHUNK 16                          // float4 per row per pass
#define NG (NTIX * 4)                      // candidate groups per (r,b): 420
#define PCAND (NG * K_)                    // 2100
#define GRID2 256
#define NEG_MASK (-1.0e9f)
#define SENT (-3.0e38f)
#define IXMAX 0x7fffffff

// ---------------------------------------------------------------------------
// Kernel 1: L2-normalize queries, write transposed layout qn[r][b][d]
// ---------------------------------------------------------------------------
__global__ __launch_bounds__(64) void knorm_kernel(const float* __restrict__ q,
                                                   float* __restrict__ qn) {
    int pair = blockIdx.x;          // 0 .. B*R-1
    int b = pair / R_;
    int r = pair % R_;
    int lane = threadIdx.x;
    const float4* src = (const float4*)(q + ((size_t)(b * R_ + r)) * D_);
    float4 x0 = src[lane * 2];
    float4 x1 = src[lane * 2 + 1];
    float ss = x0.x * x0.x + x0.y * x0.y + x0.z * x0.z + x0.w * x0.w +
               x1.x * x1.x + x1.y * x1.y + x1.z * x1.z + x1.w * x1.w;
#pragma unroll
    for (int off = 32; off; off >>= 1) ss += __shfl_xor(ss, off);
    float inv = 1.0f / fmaxf(sqrtf(ss), 1e-12f);
    float4 y0, y1;
    y0.x = x0.x * inv; y0.y = x0.y * inv; y0.z = x0.z * inv; y0.w = x0.w * inv;
    y1.x = x1.x * inv; y1.y = x1.y * inv; y1.z = x1.z * inv; y1.w = x1.w * inv;
    float4* dst = (float4*)(qn + ((size_t)(r * B_ + b)) * D_);
    dst[lane * 2] = y0;
    dst[lane * 2 + 1] = y1;
}

// ---------------------------------------------------------------------------
// Kernel 2: persistent blocks, 1/CU. Tile = (r, 192 rows); kb staged via
// global_load_lds (1KB contiguous per instr -> full-page HBM bursts) into a
// 2x48KB double buffer; per-wave pipeline with counted vmcnt (no barriers in
// the main loop -- each wave stages and computes only its own 48 rows).
// Compute: lane = 4g+s; s = d-split (4 lanes/row), 3 rows/lane, 16 b accs.
// LDS chunk index XOR-swizzled with (row&7) via pre-swizzled SOURCE addrs.
// ---------------------------------------------------------------------------
__global__ __launch_bounds__(256) void ksim_kernel(const float* __restrict__ kb,
                                                   const float* __restrict__ qn,
                                                   const int* __restrict__ qid,
                                                   const int* __restrict__ kbid,
                                                   float* __restrict__ pvals,
                                                   int* __restrict__ pidx) {
    __shared__ float4 qs[B_ * DF4];            // 32 KB q panel
    __shared__ float4 kbt[2][TROWS * PCHUNK];  // 2 x 48 KB kb double buffer

    const int tid = threadIdx.x;
    const int w = tid >> 6;               // wave 0..3
    const int lane = tid & 63;
    const int s = lane & 3;               // d-split
    const int g = lane >> 2;              // row group 0..15
    const int ssub = lane >> 4;           // staging: row within 1KB instr
    const int sc = lane & 15;             // staging: chunk 0..15

    const int bid = blockIdx.x;
    const int t0 = (bid * NTILES) / GRID2;
    const int t1 = ((bid + 1) * NTILES) / GRID2;

    int cur_r = -1;

    for (int ti = t0; ti < t1; ++ti) {
        const int r = ti / NTIX;
        const int tix = ti % NTIX;
        const int n0 = tix * TROWS;

        if (r != cur_r) {
            __syncthreads();              // everyone done reading old q panel
            const float4* src = (const float4*)(qn + (size_t)r * B_ * D_);
#pragma unroll
            for (int i = 0; i < 8; ++i) qs[tid + 256 * i] = src[tid + 256 * i];
            __syncthreads();
            cur_r = r;
        }

        // per-tile staging source pointers (12 x 1KB instrs per wave per pass)
        const float* srcp[12];
#pragma unroll
        for (int j = 0; j < 12; ++j) {
            int lr = w * 48 + j * 4 + ssub;          // local row 0..191
            int n = n0 + lr; if (n > N_ - 1) n = N_ - 1;
            int c = sc ^ (lr & 7);                   // source-side swizzle
            srcp[j] = kb + ((size_t)r * N_ + n) * D_ + c * 4;
        }
        // compute-side row bases
        int rowg[3], basem[3], swm[3];
#pragma unroll
        for (int m = 0; m < 3; ++m) {
            int lr = w * 48 + g + m * 16;
            rowg[m] = n0 + lr;
            basem[m] = lr * 256;                     // byte offset in buffer
            swm[m] = (lr & 7) * 16;                  // read-side swizzle key
        }

        float acc[3][B_];
        float nrm[3];
#pragma unroll
        for (int m = 0; m < 3; ++m) {
            nrm[m] = 0.0f;
#pragma unroll
            for (int b = 0; b < B_; ++b) acc[m][b] = 0.0f;
        }

        int buf = 0;
        // prologue: stage pass 0
        {
            char* dbase = (char*)&kbt[buf][0] + w * 12288;
#pragma unroll
            for (int j = 0; j < 12; ++j) {
                __builtin_amdgcn_global_load_lds(
                    (const __attribute__((address_space(1))) void*)srcp[j],
                    (__attribute__((address_space(3))) void*)(dbase + j * 1024),
                    16, 0, 0);
                srcp[j] += 64;
            }
        }

        for (int p = 0; p < NPASS; ++p) {
            if (p < NPASS - 1) {           // stage next pass into other buffer
                char* dbase = (char*)&kbt[buf ^ 1][0] + w * 12288;
#pragma unroll
                for (int j = 0; j < 12; ++j) {
                    __builtin_amdgcn_global_load_lds(
                        (const __attribute__((address_space(1))) void*)srcp[j],
                        (__attribute__((address_space(3))) void*)(dbase + j * 1024),
                        16, 0, 0);
                    srcp[j] += 64;
                }
                asm volatile("s_waitcnt vmcnt(12)" ::: "memory");
            } else {
                asm volatile("s_waitcnt vmcnt(0)" ::: "memory");
            }

            const char* kbase = (const char*)&kbt[buf][0];
            const int qoff = p * PCHUNK + s;
#pragma unroll
            for (int t = 0; t < 4; ++t) {
                float4 kv[3];
#pragma unroll
                for (int m = 0; m < 3; ++m)
                    kv[m] = *(const float4*)(kbase + basem[m] +
                                             ((t * 64 + s * 16) ^ swm[m]));
#pragma unroll
                for (int m = 0; m < 3; ++m)
                    nrm[m] += kv[m].x * kv[m].x + kv[m].y * kv[m].y +
                              kv[m].z * kv[m].z + kv[m].w * kv[m].w;
#pragma unroll
                for (int b = 0; b < B_; ++b) {
                    const float4 qv = qs[b * DF4 + qoff + t * 4];
#pragma unroll
                    for (int m = 0; m < 3; ++m)
                        acc[m][b] += kv[m].x * qv.x + kv[m].y * qv.y +
                                     kv[m].z * qv.z + kv[m].w * qv.w;
                }
            }
            buf ^= 1;
        }

        // reduce partials over the 4 s-lanes (all lanes end with totals)
        float rinv[3];
        int myid[3];
#pragma unroll
        for (int m = 0; m < 3; ++m) {
            nrm[m] += __shfl_xor(nrm[m], 1);
            nrm[m] += __shfl_xor(nrm[m], 2);
#pragma unroll
            for (int b = 0; b < B_; ++b) {
                acc[m][b] += __shfl_xor(acc[m][b], 1);
                acc[m][b] += __shfl_xor(acc[m][b], 2);
            }
            rinv[m] = 1.0f / fmaxf(sqrtf(nrm[m]), 1e-12f);
            myid[m] = (rowg[m] < N_) ? kbid[(size_t)r * N_ + rowg[m]] : -1;
        }

        // per-wave top-5 per b over its 48 rows (values 4-fold s-replicated;
        // shfl levels 4..32 suffice, and index-removal hits all copies)
        const int group = tix * 4 + w;
        for (int b = 0; b < B_; ++b) {
            const int qb = qid[b];
            float v[3];
#pragma unroll
            for (int m = 0; m < 3; ++m) {
                float sv = acc[m][b] * rinv[m];
                if (myid[m] == qb) sv = NEG_MASK;
                if (rowg[m] >= N_) sv = SENT;
                v[m] = sv;
            }
            for (int k = 0; k < K_; ++k) {
                float bv = v[0];
                int bx = rowg[0];
#pragma unroll
                for (int m = 1; m < 3; ++m)
                    if (v[m] > bv || (v[m] == bv && rowg[m] < bx)) { bv = v[m]; bx = rowg[m]; }
#pragma unroll
                for (int off = 4; off < 64; off <<= 1) {
                    float ov = __shfl_xor(bv, off);
                    int ox = __shfl_xor(bx, off);
                    if (ov > bv || (ov == bv && ox < bx)) { bv = ov; bx = ox; }
                }
                if (lane == 0) {
                    size_t o = (((size_t)r * B_ + b) * NG + group) * K_ + k;
                    pvals[o] = bv;
                    pidx[o] = bx;
                }
#pragma unroll
                for (int m = 0; m < 3; ++m)
                    if (rowg[m] == bx) v[m] = SENT;   // remove winner
            }
        }
    }
}

// ---------------------------------------------------------------------------
// Kernel 3: reduce 2100 candidates per (b,r) to final top-5.
// Per-lane running sorted top-5 + 5 shuffle-argmax extractions.
// d_out layout (all float32): scores[B][R] | vals[B][R][5] | idx[B][R][5]
// ---------------------------------------------------------------------------
__global__ __launch_bounds__(64) void ktop_kernel(const float* __restrict__ pvals,
                                                  const int* __restrict__ pidx,
                                                  float* __restrict__ out) {
    int pair = blockIdx.x;      // 0 .. B*R-1
    int b = pair / R_;
    int r = pair % R_;
    int lane = threadIdx.x;
    const float* pv = pvals + ((size_t)r * B_ + b) * PCAND;
    const int* px = pidx + ((size_t)r * B_ + b) * PCAND;

    float tv[5];
    int tx[5];
#pragma unroll
    for (int t = 0; t < 5; ++t) { tv[t] = SENT; tx[t] = IXMAX; }

    for (int j = 0; j < (PCAND + 63) / 64; ++j) {
        int c = lane + 64 * j;
        if (c < PCAND) {
            float v = pv[c];
            int ix = px[c];
            if (v > tv[4] || (v == tv[4] && ix < tx[4])) {
                tv[4] = v; tx[4] = ix;
#pragma unroll
                for (int t = 4; t > 0; --t)
                    if (tv[t] > tv[t - 1] ||
                        (tv[t] == tv[t - 1] && tx[t] < tx[t - 1])) {
                        float fv = tv[t]; tv[t] = tv[t - 1]; tv[t - 1] = fv;
                        int fx = tx[t]; tx[t] = tx[t - 1]; tx[t - 1] = fx;
                    }
            }
        }
    }

#pragma unroll
    for (int k = 0; k < K_; ++k) {
        float bv = tv[0];
        int bx = tx[0];
#pragma unroll
        for (int off = 32; off; off >>= 1) {
            float ov = __shfl_xor(bv, off);
            int ox = __shfl_xor(bx, off);
            if (ov > bv || (ov == bv && ox < bx)) { bv = ov; bx = ox; }
        }
        if (lane == 0) {
            int p = b * R_ + r;
            if (k == 0) out[p] = bv;                       // similarity_scores
            out[B_ * R_ + (size_t)p * K_ + k] = bv;        // top_vals
            out[B_ * R_ + (size_t)B_ * R_ * K_ + (size_t)p * K_ + k] = (float)bx; // top_idx
        }
        // remove winner from this lane's sorted list (forward shift)
        bool f0 = (tx[0] == bx);
        bool f1 = f0 || (tx[1] == bx);
        bool f2 = f1 || (tx[2] == bx);
        bool f3 = f2 || (tx[3] == bx);
        bool f4 = f3 || (tx[4] == bx);
        if (f0) { tv[0] = tv[1]; tx[0] = tx[1]; }
        if (f1) { tv[1] = tv[2]; tx[1] = tx[2]; }
        if (f2) { tv[2] = tv[3]; tx[2] = tx[3]; }
        if (f3) { tv[3] = tv[4]; tx[3] = tx[4]; }
        if (f4) { tv[4] = SENT; tx[4] = IXMAX; }
    }
}

// ---------------------------------------------------------------------------
extern "C" void kernel_launch(void* const* d_in, const int* in_sizes, int n_in,
                              void* d_out, int out_size, void* d_ws, size_t ws_size,
                              hipStream_t stream) {
    const float* q    = (const float*)d_in[0];   // [B,R,D] fp32
    const float* kb   = (const float*)d_in[1];   // [R,N,D] fp32
    const int*   qid  = (const int*)d_in[2];     // [B]
    const int*   kbid = (const int*)d_in[3];     // [R,N]
    float* out = (float*)d_out;

    float* qn    = (float*)d_ws;                             // R*B*D floats
    float* pvals = qn + (size_t)R_ * B_ * D_;                // R*B*NG*K floats
    int*   pidx  = (int*)(pvals + (size_t)R_ * B_ * NG * K_);

    knorm_kernel<<<B_ * R_, 64, 0, stream>>>(q, qn);
    ksim_kernel<<<GRID2, 256, 0, stream>>>(kb, qn, qid, kbid, pvals, pidx);
    ktop_kernel<<<B_ * R_, 64, 0, stream>>>(pvals, pidx, out);
}

// Round 6
// 659.281 us; speedup vs baseline: 1.2845x; 1.2845x over previous
//
#include <hip/hip_runtime.h>
#include <stddef.h>
#include <stdint.h>

// Problem constants (AnatomicalTextEnhancer): B=16, R=29, D=512, N=20000, k=5
#define B_ 16
#define R_ 29
#define D_ 512
#define N_ 20000
#define K_ 5
#define TILE 256                           // rows per block (4 waves x 64)
#define NTIX ((N_ + TILE - 1) / TILE)      // 79 tiles per r
#define NG (NTIX * 4)                      // candidate groups per (r,b): 316
#define PCAND (NG * K_)                    // 1580
#define NPASS 16                           // d passes, 128B/row/pass
#define NEG_MASK (-1.0e9f)
#define SENT (-3.0e38f)
#define IXMAX 0x7fffffff

// ---------------------------------------------------------------------------
// Kernel 1: L2-normalize queries, write transposed layout qn[r][b][d]
// ---------------------------------------------------------------------------
__global__ __launch_bounds__(64) void knorm_kernel(const float* __restrict__ q,
                                                   float* __restrict__ qn) {
    int pair = blockIdx.x;          // 0 .. B*R-1
    int b = pair / R_;
    int r = pair % R_;
    int lane = threadIdx.x;
    const float4* src = (const float4*)(q + ((size_t)(b * R_ + r)) * D_);
    float4 x0 = src[lane * 2];
    float4 x1 = src[lane * 2 + 1];
    float ss = x0.x * x0.x + x0.y * x0.y + x0.z * x0.z + x0.w * x0.w +
               x1.x * x1.x + x1.y * x1.y + x1.z * x1.z + x1.w * x1.w;
#pragma unroll
    for (int off = 32; off; off >>= 1) ss += __shfl_xor(ss, off);
    float inv = 1.0f / fmaxf(sqrtf(ss), 1e-12f);
    float4 y0, y1;
    y0.x = x0.x * inv; y0.y = x0.y * inv; y0.z = x0.z * inv; y0.w = x0.w * inv;
    y1.x = x1.x * inv; y1.y = x1.y * inv; y1.z = x1.z * inv; y1.w = x1.w * inv;
    float4* dst = (float4*)(qn + ((size_t)(r * B_ + b)) * D_);
    dst[lane * 2] = y0;
    dst[lane * 2 + 1] = y1;
}

// ---------------------------------------------------------------------------
// Kernel 2: block = (r, 256-row tile), 4 waves x 64 rows, ROW-PER-LANE.
// Per pass (128B/row): wave stages its 64 rows via 8 global_load_lds
// (each: 8 rows x 128B, linear LDS dest, XOR-swizzled source) into a
// 2x32KB double buffer; counted vmcnt(8); NO barriers in the loop.
// Compute: lane reads its own row's 8 float4 from LDS (swizzle-read,
// 8 lanes/4-bank group = b128 minimum); q operands are WAVE-UNIFORM ->
// s_load into SGPRs (v_fmac acc, s_q, v_kb). Lane ends with the full
// dot for its row (no cross-lane reduction).
// ---------------------------------------------------------------------------
__global__ __launch_bounds__(256) void ksim_kernel(const float* __restrict__ kb,
                                                   const float* __restrict__ qn,
                                                   const int* __restrict__ qid,
                                                   const int* __restrict__ kbid,
                                                   float* __restrict__ pvals,
                                                   int* __restrict__ pidx) {
    __shared__ float4 kbt[2][TILE * 8];   // 2 x 32 KB
    const int r = blockIdx.y;
    const int n0 = blockIdx.x * TILE;
    const int tid = threadIdx.x;
    const int w = tid >> 6;
    const int lane = tid & 63;
    const int k7 = lane & 7;              // read-side swizzle key

    const float* qr = qn + (size_t)r * B_ * D_;   // uniform base -> s_loads
    const int rowi = n0 + w * 64 + lane;          // this lane's row

    // staging sources: instr j covers local rows j*8..j*8+7 (128B each);
    // lane l -> row j*8+(l>>3), chunk slot l&7 gets source chunk (l&7)^(l>>3)
    const float* srcj[8];
#pragma unroll
    for (int j = 0; j < 8; ++j) {
        int lr = j * 8 + (lane >> 3);
        int n = n0 + w * 64 + lr;
        if (n > N_ - 1) n = N_ - 1;                  // clamp tail (masked later)
        srcj[j] = kb + ((size_t)r * N_ + n) * D_ + (((lane & 7) ^ (lane >> 3)) * 4);
    }

    float acc[B_];
    float nrm = 0.0f;
#pragma unroll
    for (int b = 0; b < B_; ++b) acc[b] = 0.0f;

    // prologue: stage pass 0 into buf 0
    {
        char* d0 = (char*)&kbt[0][(w * 64) * 8];
#pragma unroll
        for (int j = 0; j < 8; ++j) {
            __builtin_amdgcn_global_load_lds(
                (const __attribute__((address_space(1))) void*)srcj[j],
                (__attribute__((address_space(3))) void*)(d0 + j * 1024),
                16, 0, 0);
            srcj[j] += 32;
        }
    }

    for (int p = 0; p < NPASS; ++p) {
        if (p < NPASS - 1) {              // stage pass p+1 into other buffer
            char* dn = (char*)&kbt[(p + 1) & 1][(w * 64) * 8];
#pragma unroll
            for (int j = 0; j < 8; ++j) {
                __builtin_amdgcn_global_load_lds(
                    (const __attribute__((address_space(1))) void*)srcj[j],
                    (__attribute__((address_space(3))) void*)(dn + j * 1024),
                    16, 0, 0);
                srcj[j] += 32;
            }
            asm volatile("s_waitcnt vmcnt(8)" ::: "memory");
        } else {
            asm volatile("s_waitcnt vmcnt(0)" ::: "memory");
        }

        const float4* kl = &kbt[p & 1][(w * 64 + lane) * 8];
        const float* qp = qr + p * 32;
#pragma unroll
        for (int c = 0; c < 8; ++c) {
            float4 kv = kl[c ^ k7];       // conflict-optimal swizzled read
            nrm += kv.x * kv.x + kv.y * kv.y + kv.z * kv.z + kv.w * kv.w;
#pragma unroll
            for (int b = 0; b < B_; ++b) {
                const float4 qv = *(const float4*)(qp + b * D_ + c * 4); // s_load
                acc[b] += kv.x * qv.x + kv.y * qv.y + kv.z * qv.z + kv.w * qv.w;
            }
        }
    }

    // finalize: normalize, mask, per-wave top-5 per b (lane-per-row values)
    float rinv = 1.0f / fmaxf(sqrtf(nrm), 1e-12f);
    int myid = (rowi < N_) ? kbid[(size_t)r * N_ + rowi] : -1;

    const int group = blockIdx.x * 4 + w;
    for (int b = 0; b < B_; ++b) {
        const int qb = qid[b];            // uniform -> scalar load
        float v = acc[b] * rinv;
        if (myid == qb) v = NEG_MASK;
        if (rowi >= N_) v = SENT;
        for (int k = 0; k < K_; ++k) {
            float bv = v;
            int bx = rowi;
#pragma unroll
            for (int off = 1; off < 64; off <<= 1) {
                float ov = __shfl_xor(bv, off);
                int ox = __shfl_xor(bx, off);
                if (ov > bv || (ov == bv && ox < bx)) { bv = ov; bx = ox; }
            }
            if (lane == 0) {
                size_t o = (((size_t)r * B_ + b) * NG + group) * K_ + k;
                pvals[o] = bv;
                pidx[o] = bx;
            }
            if (rowi == bx) v = SENT;     // remove winner
        }
    }
}

// ---------------------------------------------------------------------------
// Kernel 3: reduce 1580 candidates per (b,r) to final top-5.
// Per-lane running sorted top-5 + 5 shuffle-argmax extractions.
// d_out layout (all float32): scores[B][R] | vals[B][R][5] | idx[B][R][5]
// ---------------------------------------------------------------------------
__global__ __launch_bounds__(64) void ktop_kernel(const float* __restrict__ pvals,
                                                  const int* __restrict__ pidx,
                                                  float* __restrict__ out) {
    int pair = blockIdx.x;      // 0 .. B*R-1
    int b = pair / R_;
    int r = pair % R_;
    int lane = threadIdx.x;
    const float* pv = pvals + ((size_t)r * B_ + b) * PCAND;
    const int* px = pidx + ((size_t)r * B_ + b) * PCAND;

    float tv[5];
    int tx[5];
#pragma unroll
    for (int t = 0; t < 5; ++t) { tv[t] = SENT; tx[t] = IXMAX; }

    for (int j = 0; j < (PCAND + 63) / 64; ++j) {
        int c = lane + 64 * j;
        if (c < PCAND) {
            float v = pv[c];
            int ix = px[c];
            if (v > tv[4] || (v == tv[4] && ix < tx[4])) {
                tv[4] = v; tx[4] = ix;
#pragma unroll
                for (int t = 4; t > 0; --t)
                    if (tv[t] > tv[t - 1] ||
                        (tv[t] == tv[t - 1] && tx[t] < tx[t - 1])) {
                        float fv = tv[t]; tv[t] = tv[t - 1]; tv[t - 1] = fv;
                        int fx = tx[t]; tx[t] = tx[t - 1]; tx[t - 1] = fx;
                    }
            }
        }
    }

#pragma unroll
    for (int k = 0; k < K_; ++k) {
        float bv = tv[0];
        int bx = tx[0];
#pragma unroll
        for (int off = 32; off; off >>= 1) {
            float ov = __shfl_xor(bv, off);
            int ox = __shfl_xor(bx, off);
            if (ov > bv || (ov == bv && ox < bx)) { bv = ov; bx = ox; }
        }
        if (lane == 0) {
            int p = b * R_ + r;
            if (k == 0) out[p] = bv;                       // similarity_scores
            out[B_ * R_ + (size_t)p * K_ + k] = bv;        // top_vals
            out[B_ * R_ + (size_t)B_ * R_ * K_ + (size_t)p * K_ + k] = (float)bx; // top_idx
        }
        // remove winner from this lane's sorted list (forward shift)
        bool f0 = (tx[0] == bx);
        bool f1 = f0 || (tx[1] == bx);
        bool f2 = f1 || (tx[2] == bx);
        bool f3 = f2 || (tx[3] == bx);
        bool f4 = f3 || (tx[4] == bx);
        if (f0) { tv[0] = tv[1]; tx[0] = tx[1]; }
        if (f1) { tv[1] = tv[2]; tx[1] = tx[2]; }
        if (f2) { tv[2] = tv[3]; tx[2] = tx[3]; }
        if (f3) { tv[3] = tv[4]; tx[3] = tx[4]; }
        if (f4) { tv[4] = SENT; tx[4] = IXMAX; }
    }
}

// ---------------------------------------------------------------------------
extern "C" void kernel_launch(void* const* d_in, const int* in_sizes, int n_in,
                              void* d_out, int out_size, void* d_ws, size_t ws_size,
                              hipStream_t stream) {
    const float* q    = (const float*)d_in[0];   // [B,R,D] fp32
    const float* kb   = (const float*)d_in[1];   // [R,N,D] fp32
    const int*   qid  = (const int*)d_in[2];     // [B]
    const int*   kbid = (const int*)d_in[3];     // [R,N]
    float* out = (float*)d_out;

    float* qn    = (float*)d_ws;                             // R*B*D floats
    float* pvals = qn + (size_t)R_ * B_ * D_;                // R*B*NG*K floats
    int*   pidx  = (int*)(pvals + (size_t)R_ * B_ * NG * K_);

    knorm_kernel<<<B_ * R_, 64, 0, stream>>>(q, qn);
    dim3 g2(NTIX, R_);
    ksim_kernel<<<g2, 256, 0, stream>>>(kb, qn, qid, kbid, pvals, pidx);
    ktop_kernel<<<B_ * R_, 64, 0, stream>>>(pvals, pidx, out);
}

// Round 7
// 513.309 us; speedup vs baseline: 1.6498x; 1.2844x over previous
//
#include <hip/hip_runtime.h>
#include <stddef.h>
#include <stdint.h>

// Problem constants (AnatomicalTextEnhancer): B=16, R=29, D=512, N=20000, k=5
#define B_ 16
#define R_ 29
#define D_ 512
#define DF4 128                            // float4 per row
#define N_ 20000
#define K_ 5
#define TILE 128                           // rows per block (4 waves x 32)
#define NTIX ((N_ + TILE - 1) / TILE)      // 157 tiles per r
#define NG (NTIX * 4)                      // candidate groups per (r,b): 628
#define PCAND (NG * K_)                    // 3140
#define NEG_MASK (-1.0e9f)
#define SENT (-3.0e38f)
#define IXMAX 0x7fffffff

// ---------------------------------------------------------------------------
// Kernel 1: L2-normalize queries, write transposed layout qn[r][b][d]
// ---------------------------------------------------------------------------
__global__ __launch_bounds__(64) void knorm_kernel(const float* __restrict__ q,
                                                   float* __restrict__ qn) {
    int pair = blockIdx.x;          // 0 .. B*R-1
    int b = pair / R_;
    int r = pair % R_;
    int lane = threadIdx.x;
    const float4* src = (const float4*)(q + ((size_t)(b * R_ + r)) * D_);
    float4 x0 = src[lane * 2];
    float4 x1 = src[lane * 2 + 1];
    float ss = x0.x * x0.x + x0.y * x0.y + x0.z * x0.z + x0.w * x0.w +
               x1.x * x1.x + x1.y * x1.y + x1.z * x1.z + x1.w * x1.w;
#pragma unroll
    for (int off = 32; off; off >>= 1) ss += __shfl_xor(ss, off);
    float inv = 1.0f / fmaxf(sqrtf(ss), 1e-12f);
    float4 y0, y1;
    y0.x = x0.x * inv; y0.y = x0.y * inv; y0.z = x0.z * inv; y0.w = x0.w * inv;
    y1.x = x1.x * inv; y1.y = x1.y * inv; y1.z = x1.z * inv; y1.w = x1.w * inv;
    float4* dst = (float4*)(qn + ((size_t)(r * B_ + b)) * D_);
    dst[lane * 2] = y0;
    dst[lane * 2 + 1] = y1;
}

// ---------------------------------------------------------------------------
// Kernel 2: A/B vs round-4 best: 8-lane d-split (FULL 128B line per row per
// instruction; no L1-reuse dependence). lane = 8g+s: g=row group (8 rows),
// s=d-split (8 lanes/row). TM=4 rows/lane -> 32 rows/wave, 128 rows/block.
// kb read direct from global (no staging); q panel in LDS, 8-unique-addr
// broadcast reads (conflict-free). Depth-1 register prefetch of next p.
// Dot partials reduced over the 8 s-lanes at the end (3 shfl_xor).
// ---------------------------------------------------------------------------
__global__ __launch_bounds__(256) void ksim_kernel(const float* __restrict__ kb,
                                                   const float* __restrict__ qn,
                                                   const int* __restrict__ qid,
                                                   const int* __restrict__ kbid,
                                                   float* __restrict__ pvals,
                                                   int* __restrict__ pidx) {
    __shared__ float4 qs[B_ * DF4];       // 32 KB q panel
    const int r = blockIdx.y;
    const int n0 = blockIdx.x * TILE;
    const int tid = threadIdx.x;

    // stage q panel once (coalesced), single barrier
    {
        const float4* src = (const float4*)(qn + (size_t)r * B_ * D_);
#pragma unroll
        for (int i = 0; i < 32; ++i) qs[tid + 256 * i] = src[tid + 256 * i];
    }
    __syncthreads();

    const int w = tid >> 6;
    const int lane = tid & 63;
    const int g = lane >> 3;              // row group 0..7
    const int s = lane & 7;               // d-split 0..7

    int rowi[4];
    const float4* rowp[4];
    float acc[4][B_];
    float nrm[4];
#pragma unroll
    for (int m = 0; m < 4; ++m) {
        rowi[m] = n0 + w * 32 + g + m * 8;
        int rc = rowi[m] < N_ ? rowi[m] : N_ - 1;   // clamp tail (masked later)
        rowp[m] = (const float4*)(kb + (size_t)r * N_ * D_ + (size_t)rc * D_) + s;
        nrm[m] = 0.0f;
#pragma unroll
        for (int b = 0; b < B_; ++b) acc[m][b] = 0.0f;
    }

    // main loop: p = 0..15; lane's chunk = float4 #(8p + s) of each row.
    // One instruction = 8 rows x 128B contiguous = 8 FULL cache lines.
    float4 kv[4], kn[4];
#pragma unroll
    for (int m = 0; m < 4; ++m) kv[m] = rowp[m][0];

    for (int p = 0; p < 16; ++p) {
        if (p < 15) {
#pragma unroll
            for (int m = 0; m < 4; ++m) kn[m] = rowp[m][(p + 1) * 8];
        }
#pragma unroll
        for (int m = 0; m < 4; ++m)
            nrm[m] += kv[m].x * kv[m].x + kv[m].y * kv[m].y +
                      kv[m].z * kv[m].z + kv[m].w * kv[m].w;
#pragma unroll
        for (int b = 0; b < B_; ++b) {
            const float4 qv = qs[b * DF4 + p * 8 + s];   // 8 uniq addrs, bcast
#pragma unroll
            for (int m = 0; m < 4; ++m)
                acc[m][b] += kv[m].x * qv.x + kv[m].y * qv.y +
                             kv[m].z * qv.z + kv[m].w * qv.w;
        }
#pragma unroll
        for (int m = 0; m < 4; ++m) kv[m] = kn[m];
    }

    // reduce partials over the 8 s-lanes (all lanes end with totals)
#pragma unroll
    for (int m = 0; m < 4; ++m) {
        nrm[m] += __shfl_xor(nrm[m], 1);
        nrm[m] += __shfl_xor(nrm[m], 2);
        nrm[m] += __shfl_xor(nrm[m], 4);
#pragma unroll
        for (int b = 0; b < B_; ++b) {
            acc[m][b] += __shfl_xor(acc[m][b], 1);
            acc[m][b] += __shfl_xor(acc[m][b], 2);
            acc[m][b] += __shfl_xor(acc[m][b], 4);
        }
    }

    // finalize norms + masks
    float rinv[4];
    int myid[4];
#pragma unroll
    for (int m = 0; m < 4; ++m) {
        rinv[m] = 1.0f / fmaxf(sqrtf(nrm[m]), 1e-12f);
        myid[m] = (rowi[m] < N_) ? kbid[(size_t)r * N_ + rowi[m]] : -1;
    }

    // per-wave top-5 per b over its 32 rows (values 8-fold s-replicated;
    // identical copies keep argmax + index-removal consistent)
    const int group = blockIdx.x * 4 + w;
    for (int b = 0; b < B_; ++b) {
        const int qb = qid[b];            // uniform -> scalar load
        float v[4];
#pragma unroll
        for (int m = 0; m < 4; ++m) {
            float sv = acc[m][b] * rinv[m];
            if (myid[m] == qb) sv = NEG_MASK;
            if (rowi[m] >= N_) sv = SENT;
            v[m] = sv;
        }
        for (int k = 0; k < K_; ++k) {
            float bv = v[0];
            int bx = rowi[0];
#pragma unroll
            for (int m = 1; m < 4; ++m)
                if (v[m] > bv || (v[m] == bv && rowi[m] < bx)) { bv = v[m]; bx = rowi[m]; }
#pragma unroll
            for (int off = 8; off < 64; off <<= 1) {
                float ov = __shfl_xor(bv, off);
                int ox = __shfl_xor(bx, off);
                if (ov > bv || (ov == bv && ox < bx)) { bv = ov; bx = ox; }
            }
            if (lane == 0) {
                size_t o = (((size_t)r * B_ + b) * NG + group) * K_ + k;
                pvals[o] = bv;
                pidx[o] = bx;
            }
#pragma unroll
            for (int m = 0; m < 4; ++m)
                if (rowi[m] == bx) v[m] = SENT;   // remove winner (all copies)
        }
    }
}

// ---------------------------------------------------------------------------
// Kernel 3: reduce 3140 candidates per (b,r) to final top-5.
// Per-lane running sorted top-5 + 5 shuffle-argmax extractions.
// d_out layout (all float32): scores[B][R] | vals[B][R][5] | idx[B][R][5]
// ---------------------------------------------------------------------------
__global__ __launch_bounds__(64) void ktop_kernel(const float* __restrict__ pvals,
                                                  const int* __restrict__ pidx,
                                                  float* __restrict__ out) {
    int pair = blockIdx.x;      // 0 .. B*R-1
    int b = pair / R_;
    int r = pair % R_;
    int lane = threadIdx.x;
    const float* pv = pvals + ((size_t)r * B_ + b) * PCAND;
    const int* px = pidx + ((size_t)r * B_ + b) * PCAND;

    float tv[5];
    int tx[5];
#pragma unroll
    for (int t = 0; t < 5; ++t) { tv[t] = SENT; tx[t] = IXMAX; }

    for (int j = 0; j < (PCAND + 63) / 64; ++j) {
        int c = lane + 64 * j;
        if (c < PCAND) {
            float v = pv[c];
            int ix = px[c];
            if (v > tv[4] || (v == tv[4] && ix < tx[4])) {
                tv[4] = v; tx[4] = ix;
#pragma unroll
                for (int t = 4; t > 0; --t)
                    if (tv[t] > tv[t - 1] ||
                        (tv[t] == tv[t - 1] && tx[t] < tx[t - 1])) {
                        float fv = tv[t]; tv[t] = tv[t - 1]; tv[t - 1] = fv;
                        int fx = tx[t]; tx[t] = tx[t - 1]; tx[t - 1] = fx;
                    }
            }
        }
    }

#pragma unroll
    for (int k = 0; k < K_; ++k) {
        float bv = tv[0];
        int bx = tx[0];
#pragma unroll
        for (int off = 32; off; off >>= 1) {
            float ov = __shfl_xor(bv, off);
            int ox = __shfl_xor(bx, off);
            if (ov > bv || (ov == bv && ox < bx)) { bv = ov; bx = ox; }
        }
        if (lane == 0) {
            int p = b * R_ + r;
            if (k == 0) out[p] = bv;                       // similarity_scores
            out[B_ * R_ + (size_t)p * K_ + k] = bv;        // top_vals
            out[B_ * R_ + (size_t)B_ * R_ * K_ + (size_t)p * K_ + k] = (float)bx; // top_idx
        }
        // remove winner from this lane's sorted list (forward shift)
        bool f0 = (tx[0] == bx);
        bool f1 = f0 || (tx[1] == bx);
        bool f2 = f1 || (tx[2] == bx);
        bool f3 = f2 || (tx[3] == bx);
        bool f4 = f3 || (tx[4] == bx);
        if (f0) { tv[0] = tv[1]; tx[0] = tx[1]; }
        if (f1) { tv[1] = tv[2]; tx[1] = tx[2]; }
        if (f2) { tv[2] = tv[3]; tx[2] = tx[3]; }
        if (f3) { tv[3] = tv[4]; tx[3] = tx[4]; }
        if (f4) { tv[4] = SENT; tx[4] = IXMAX; }
    }
}

// ---------------------------------------------------------------------------
extern "C" void kernel_launch(void* const* d_in, const int* in_sizes, int n_in,
                              void* d_out, int out_size, void* d_ws, size_t ws_size,
                              hipStream_t stream) {
    const float* q    = (const float*)d_in[0];   // [B,R,D] fp32
    const float* kb   = (const float*)d_in[1];   // [R,N,D] fp32
    const int*   qid  = (const int*)d_in[2];     // [B]
    const int*   kbid = (const int*)d_in[3];     // [R,N]
    float* out = (float*)d_out;

    float* qn    = (float*)d_ws;                             // R*B*D floats
    float* pvals = qn + (size_t)R_ * B_ * D_;                // R*B*NG*K floats
    int*   pidx  = (int*)(pvals + (size_t)R_ * B_ * NG * K_);

    knorm_kernel<<<B_ * R_, 64, 0, stream>>>(q, qn);
    dim3 g2(NTIX, R_);
    ksim_kernel<<<g2, 256, 0, stream>>>(kb, qn, qid, kbid, pvals, pidx);
    ktop_kernel<<<B_ * R_, 64, 0, stream>>>(pvals, pidx, out);
}